// Round 9
// baseline (217.758 us; speedup 1.0000x reference)
//
#include <hip/hip_runtime.h>
#include <hip/hip_bf16.h>
#include <stdint.h>

#define K_DIM 512
#define N_DIM 512
#define BM 64
#define BN 256
#define PHASE_K 64                        // fp32 k-columns per LDS phase
#define PHASE_FLOATS (BM * PHASE_K)       // 4096 floats = 16 KiB
#define NBUF 3

typedef __bf16 bf16x8 __attribute__((ext_vector_type(8)));
typedef float floatx4 __attribute__((ext_vector_type(4)));

__device__ __forceinline__ bf16x8 cvt8(float4 a, float4 b) {
    bf16x8 r;
    r[0] = (__bf16)a.x; r[1] = (__bf16)a.y; r[2] = (__bf16)a.z; r[3] = (__bf16)a.w;
    r[4] = (__bf16)b.x; r[5] = (__bf16)b.y; r[6] = (__bf16)b.z; r[7] = (__bf16)b.w;
    return r;
}

// Pre-convert W [N,K] fp32 -> fragment-linear bf16:
// wf[((ntg*16+kcg)*64 + lane)*8 + j] = W[ntg*16+(lane&15)][kcg*32+(lane>>4)*8+j]
__global__ __launch_bounds__(512) void wconv_kernel(const float* __restrict__ w,
                                                    __bf16* __restrict__ wf) {
    int t = blockIdx.x * 512 + threadIdx.x;     // 0..32767
    int lane = t & 63, slot = t >> 6;           // slot = ntg*16+kcg
    int n = ((slot >> 4) << 4) + (lane & 15);
    int k = ((slot & 15) << 5) + ((lane >> 4) << 3);
    const float* src = w + (size_t)n * K_DIM + k;
    float4 f0 = *(const float4*)src;
    float4 f1 = *(const float4*)(src + 4);
    *(bf16x8*)(wf + (size_t)t * 8) = cvt8(f0, f1);
}

// Stage one 64x64 fp32 slab of x (16 KiB) via global_load_lds, 2 ops/thread
// (512 threads). LDS physical layout: row-major [64][64] fp32 (256 B/row);
// physical in-row byte p holds source in-row byte p ^ ((row&7)<<4). Linear LDS
// dest (wave-uniform base + lane*16) + inverse-swizzled global source (r5/r6
// verified).
__device__ __forceinline__ void stage_phase(const float* __restrict__ x,
                                            int rowBase, int kBase,
                                            float* ldsBuf, int wid, int lane) {
    #pragma unroll
    for (int i = 0; i < 2; ++i) {
        int sl = i * 8 + wid;                    // 0..15, wave-uniform
        int row = sl * 4 + (lane >> 4);          // 0..63
        int srcByte = ((lane & 15) << 4) ^ ((row & 7) << 4);
        const float* g = x + (size_t)(rowBase + row) * K_DIM + kBase + (srcByte >> 2);
        float* l = ldsBuf + sl * 256;            // 1 KiB per slot, wave-uniform
        __builtin_amdgcn_global_load_lds(
            (const __attribute__((address_space(1))) void*)g,
            (__attribute__((address_space(3))) void*)l, 16, 0, 0);
    }
}

// Read A fragment from swizzled fp32 slab -> bf16x8; each 16B half at its OWN
// swizzled address (round-4 lesson; r5/r6 verified at CHUNK_K=64).
__device__ __forceinline__ bf16x8 read_afrag(const float* ldsBuf, int mg, int rt,
                                             int kcl, int lane) {
    int row = mg * 32 + rt * 16 + (lane & 15);
    int sw = (row & 7) << 4;
    int b0 = kcl * 128 + ((lane >> 4) << 5);     // source byte-in-row 0..224
    const char* rb = (const char*)(ldsBuf + row * PHASE_K);
    float4 fa = *(const float4*)(rb + (b0 ^ sw));
    float4 fb = *(const float4*)(rb + ((b0 + 16) ^ sw));
    return cvt8(fa, fb);
}

// Load the wave's W fragments for phase p into registers (8 vm ops if USE_WF).
template <bool USE_WF>
__device__ __forceinline__ void load_wfrag(bf16x8 (&dst)[4][2], int p,
                                           const __bf16* __restrict__ wf,
                                           const float* __restrict__ w,
                                           int ntgBase, int lane) {
    #pragma unroll
    for (int nt = 0; nt < 4; ++nt) {
        int ntg = ntgBase + nt;
        #pragma unroll
        for (int kcl = 0; kcl < 2; ++kcl) {
            int kcg = p * 2 + kcl;
            if (USE_WF) {
                dst[nt][kcl] = *(const bf16x8*)(wf + (size_t)(((ntg << 4) + kcg) * 64 + lane) * 8);
            } else {
                int n = (ntg << 4) + (lane & 15);
                const float* s = w + (size_t)n * K_DIM + (kcg << 5) + ((lane >> 4) << 3);
                dst[nt][kcl] = cvt8(*(const float4*)s, *(const float4*)(s + 4));
            }
        }
    }
}

// One 64x256 output tile per block (grid = row-tiles x 2 col-halves; consecutive
// block IDs share x rows -> second read L2/L3-hits). 8 waves = 2M x 4N, wave
// tile 32x64. Per phase (K=64): issue wf(p)->regs FIRST, stage(p+1) LAST, then
// s_waitcnt vmcnt(2) retires {stage(p), wf(p)} and keeps ONLY stage(p+1) in
// flight across the barrier. Compute phase issues ZERO vm ops, so no wait ever
// chains behind the in-flight HBM stage (in-order vmcnt retirement, m135).
// NBUF=3 removes the stage-vs-prior-reader race (buffer written at phase p+1
// was last read at phase p-2, two barriers earlier).
template <bool USE_WF>
__global__ __launch_bounds__(512, 4) void gemm_kernel(
    const float* __restrict__ x, const float* __restrict__ xscale,
    const __bf16* __restrict__ wf, const float* __restrict__ w,
    const float* __restrict__ wscale, float* __restrict__ out)
{
    __shared__ __align__(16) float lds[NBUF * PHASE_FLOATS];   // 48 KiB
    const int t = threadIdx.x;
    const int lane = t & 63;
    const int wid = t >> 6;                      // 0..7
    const int mg = wid >> 2;                     // 0..1  (32-row half)
    const int ng = wid & 3;                      // 0..3  (64-col quarter)
    const int laneR = lane & 15;

    const int bid = blockIdx.x;
    const int tile = bid >> 1;
    const int half = bid & 1;
    const int rowb = tile * BM;
    const int ntgBase = half * 16 + ng * 4;

    floatx4 acc[2][4];
    #pragma unroll
    for (int i = 0; i < 2; ++i)
        #pragma unroll
        for (int j = 0; j < 4; ++j) acc[i][j] = (floatx4)0.f;

    bf16x8 wfr[4][2];

    // prologue: stage(0) is the oldest vm op
    stage_phase(x, rowb, 0, lds, wid, lane);
    __builtin_amdgcn_sched_barrier(0);

    #pragma unroll
    for (int p = 0; p < 8; ++p) {
        // [1] wf(p) -> registers (older than stage(p+1))
        load_wfrag<USE_WF>(wfr, p, wf, w, ntgBase, lane);
        __builtin_amdgcn_sched_barrier(0);

        // [2] stage(p+1) issued LAST -> the only ops left in flight after [3]
        if (p < 7) {
            stage_phase(x, rowb, (p + 1) * PHASE_K,
                        lds + ((p + 1) % NBUF) * PHASE_FLOATS, wid, lane);
            __builtin_amdgcn_sched_barrier(0);
            // [3] retire {stage(p), wf(p)}; keep stage(p+1) (2 newest) in flight
            asm volatile("s_waitcnt vmcnt(2) lgkmcnt(0)\n\ts_barrier" ::: "memory");
        } else {
            asm volatile("s_waitcnt vmcnt(0) lgkmcnt(0)\n\ts_barrier" ::: "memory");
        }

        // [4] compute from buf[p%3]: LDS reads + MFMA only, zero vm ops
        const float* cb = lds + (p % NBUF) * PHASE_FLOATS;
        #pragma unroll
        for (int kcl = 0; kcl < 2; ++kcl) {
            bf16x8 ax[2];
            #pragma unroll
            for (int rt = 0; rt < 2; ++rt)
                ax[rt] = read_afrag(cb, mg, rt, kcl, lane);
            #pragma unroll
            for (int nt = 0; nt < 4; ++nt)
                #pragma unroll
                for (int rt = 0; rt < 2; ++rt)
                    acc[rt][nt] = __builtin_amdgcn_mfma_f32_16x16x32_bf16(
                        wfr[nt][kcl], ax[rt], acc[rt][nt], 0, 0, 0);
        }
    }

    // epilogue: dequant + fp32 float4 stores (4 consecutive n per lane)
    #pragma unroll
    for (int rt = 0; rt < 2; ++rt) {
        int m = rowb + mg * 32 + rt * 16 + laneR;
        float xs = xscale[m];
        #pragma unroll
        for (int nt = 0; nt < 4; ++nt) {
            int nb = half * BN + ng * 64 + (nt << 4) + ((lane >> 4) << 2);
            float4 wsc = *(const float4*)(wscale + nb);
            floatx4 a = acc[rt][nt];
            float4 o;
            o.x = a[0] * xs * wsc.x;
            o.y = a[1] * xs * wsc.y;
            o.z = a[2] * xs * wsc.z;
            o.w = a[3] * xs * wsc.w;
            *(float4*)(out + (size_t)m * N_DIM + nb) = o;
        }
    }
}

extern "C" void kernel_launch(void* const* d_in, const int* in_sizes, int n_in,
                              void* d_out, int out_size, void* d_ws, size_t ws_size,
                              hipStream_t stream) {
    const float* x      = (const float*)d_in[0];
    const float* xscale = (const float*)d_in[1];
    const float* w      = (const float*)d_in[2];
    const float* wscale = (const float*)d_in[3];
    float* out          = (float*)d_out;

    const int M = in_sizes[0] / K_DIM;            // 131072
    const int grid = (M / BM) * 2;                // 4096 (row-tile x col-half)

    if (ws_size >= (size_t)(N_DIM * K_DIM * sizeof(unsigned short))) {
        __bf16* wfp = (__bf16*)d_ws;
        wconv_kernel<<<dim3(64), dim3(512), 0, stream>>>(w, wfp);
        gemm_kernel<true><<<dim3(grid), dim3(512), 0, stream>>>(
            x, xscale, wfp, w, wscale, out);
    } else {
        gemm_kernel<false><<<dim3(grid), dim3(512), 0, stream>>>(
            x, xscale, nullptr, w, wscale, out);
    }
}

// Round 10
// 204.454 us; speedup vs baseline: 1.0651x; 1.0651x over previous
//
#include <hip/hip_runtime.h>
#include <hip/hip_bf16.h>
#include <stdint.h>

#define K_DIM 512
#define N_DIM 512
#define BM 64
#define BN 128
#define PHASE_K 64                        // fp32 k-columns per LDS phase
#define PHASE_FLOATS (BM * PHASE_K)       // 4096 floats = 16 KiB

typedef __bf16 bf16x8 __attribute__((ext_vector_type(8)));
typedef float floatx4 __attribute__((ext_vector_type(4)));

__device__ __forceinline__ bf16x8 cvt8(float4 a, float4 b) {
    bf16x8 r;
    r[0] = (__bf16)a.x; r[1] = (__bf16)a.y; r[2] = (__bf16)a.z; r[3] = (__bf16)a.w;
    r[4] = (__bf16)b.x; r[5] = (__bf16)b.y; r[6] = (__bf16)b.z; r[7] = (__bf16)b.w;
    return r;
}

// Pre-convert W [N,K] fp32 -> fragment-linear bf16:
// wf[((ntg*16+kcg)*64 + lane)*8 + j] = W[ntg*16+(lane&15)][kcg*32+(lane>>4)*8+j]
__global__ __launch_bounds__(512) void wconv_kernel(const float* __restrict__ w,
                                                    __bf16* __restrict__ wf) {
    int t = blockIdx.x * 512 + threadIdx.x;     // 0..32767
    int lane = t & 63, slot = t >> 6;           // slot = ntg*16+kcg
    int n = ((slot >> 4) << 4) + (lane & 15);
    int k = ((slot & 15) << 5) + ((lane >> 4) << 3);
    const float* src = w + (size_t)n * K_DIM + k;
    float4 f0 = *(const float4*)src;
    float4 f1 = *(const float4*)(src + 4);
    *(bf16x8*)(wf + (size_t)t * 8) = cvt8(f0, f1);
}

// Stage one 64x64 fp32 slab of x (16 KiB) via global_load_lds, 4 ops/thread
// (256 threads). LDS physical layout: row-major [64][64] fp32 (256 B/row);
// physical in-row byte p holds source in-row byte p ^ ((row&7)<<4). Linear LDS
// dest (wave-uniform base + lane*16) + inverse-swizzled global source (verified
// r5/r6/r9). Dest check: sl*1024 + lane*16 == row*256 + (lane&15)*16 with
// row = sl*4 + (lane>>4).  ✓
__device__ __forceinline__ void stage_phase(const float* __restrict__ x,
                                            int rowBase, int kBase,
                                            float* ldsBuf, int wid, int lane) {
    #pragma unroll
    for (int i = 0; i < 4; ++i) {
        int sl = i * 4 + wid;                    // 0..15, wave-uniform
        int row = sl * 4 + (lane >> 4);          // 0..63
        int srcByte = ((lane & 15) << 4) ^ ((row & 7) << 4);
        const float* g = x + (size_t)(rowBase + row) * K_DIM + kBase + (srcByte >> 2);
        float* l = ldsBuf + sl * 256;            // 1 KiB per slot, wave-uniform
        __builtin_amdgcn_global_load_lds(
            (const __attribute__((address_space(1))) void*)g,
            (__attribute__((address_space(3))) void*)l, 16, 0, 0);
    }
}

// Read A fragment from swizzled fp32 slab -> bf16x8; each 16B half at its OWN
// swizzled address (round-4 lesson; verified r5/r6/r9 at PHASE_K=64).
__device__ __forceinline__ bf16x8 read_afrag(const float* ldsBuf, int mg, int rt,
                                             int kcl, int lane) {
    int row = mg * 32 + rt * 16 + (lane & 15);
    int sw = (row & 7) << 4;
    int b0 = kcl * 128 + ((lane >> 4) << 5);     // source byte-in-row 0..224
    const char* rb = (const char*)(ldsBuf + row * PHASE_K);
    float4 fa = *(const float4*)(rb + (b0 ^ sw));
    float4 fb = *(const float4*)(rb + ((b0 + 16) ^ sw));
    return cvt8(fa, fb);
}

// Load the wave's W fragments for phase p into registers (8 vm ops if USE_WF).
template <bool USE_WF>
__device__ __forceinline__ void load_wfrag(bf16x8 (&dst)[4][2], int p,
                                           const __bf16* __restrict__ wf,
                                           const float* __restrict__ w,
                                           int ntgBase, int lane) {
    #pragma unroll
    for (int nt = 0; nt < 4; ++nt) {
        int ntg = ntgBase + nt;
        #pragma unroll
        for (int kcl = 0; kcl < 2; ++kcl) {
            int kcg = p * 2 + kcl;
            if (USE_WF) {
                dst[nt][kcl] = *(const bf16x8*)(wf + (size_t)(((ntg << 4) + kcg) * 64 + lane) * 8);
            } else {
                int n = (ntg << 4) + (lane & 15);
                const float* s = w + (size_t)n * K_DIM + (kcg << 5) + ((lane >> 4) << 3);
                dst[nt][kcl] = cvt8(*(const float4*)s, *(const float4*)(s + 4));
            }
        }
    }
}

// 64x128 output tile per block; 4 waves = 2M x 2N, wave tile 32x64.
// Per phase: sync (drains stage(p)) -> wf(p)->regs (OLDER in vm queue) ->
// stage(p+1) (NEWER; flies across the whole compute phase, drained by the next
// sync) -> compute from LDS+regs (wf waits leave the stage in flight: precise
// compiler vmcnt). Small blocks = 5/CU (LDS 32KB) staging independently ->
// sustained in-flight bytes instead of bursts (the r2..r9 plateau cause).
template <bool USE_WF>
__global__ __launch_bounds__(256, 4) void gemm_kernel(
    const float* __restrict__ x, const float* __restrict__ xscale,
    const __bf16* __restrict__ wf, const float* __restrict__ w,
    const float* __restrict__ wscale, float* __restrict__ out,
    int chunkPerXcd)
{
    __shared__ __align__(16) float lds[2 * PHASE_FLOATS];   // 32 KiB
    const int t = threadIdx.x;
    const int lane = t & 63;
    const int wid = t >> 6;                      // 0..3
    const int mg = wid >> 1;                     // 0..1 (32-row half)
    const int ng = wid & 1;                      // 0..1 (64-col half)
    const int laneR = lane & 15;

    // bijective XCD swizzle: XCD k owns logical ids [k*chunk, (k+1)*chunk);
    // logical id L = row-major over (rowTile, colQuarter) so the 4 col-blocks
    // of one 64-row slab are adjacent -> same XCD -> x slab L2-hits.
    const int b = blockIdx.x;
    const int L = (b & 7) * chunkPerXcd + (b >> 3);
    const int rowTile = L >> 2;
    const int col = L & 3;
    const int rowb = rowTile * BM;
    const int ntgBase = col * 8 + ng * 4;

    floatx4 acc[2][4];
    #pragma unroll
    for (int i = 0; i < 2; ++i)
        #pragma unroll
        for (int j = 0; j < 4; ++j) acc[i][j] = (floatx4)0.f;

    bf16x8 wfr[4][2];

    stage_phase(x, rowb, 0, lds, wid, lane);

    #pragma unroll
    for (int p = 0; p < 8; ++p) {
        __syncthreads();                         // stage(p) complete, buf[p&1] ready

        // wf(p) -> regs, kept OLDER than stage(p+1) in the vm queue
        load_wfrag<USE_WF>(wfr, p, wf, w, ntgBase, lane);
        __builtin_amdgcn_sched_barrier(0);

        if (p < 7)
            stage_phase(x, rowb, (p + 1) * PHASE_K,
                        &lds[((p + 1) & 1) * PHASE_FLOATS], wid, lane);
        __builtin_amdgcn_sched_barrier(0);

        // compute from buf[p&1]: ds_read + MFMA only
        const float* cb = &lds[(p & 1) * PHASE_FLOATS];
        #pragma unroll
        for (int kcl = 0; kcl < 2; ++kcl) {
            bf16x8 ax[2];
            #pragma unroll
            for (int rt = 0; rt < 2; ++rt)
                ax[rt] = read_afrag(cb, mg, rt, kcl, lane);
            #pragma unroll
            for (int nt = 0; nt < 4; ++nt)
                #pragma unroll
                for (int rt = 0; rt < 2; ++rt)
                    acc[rt][nt] = __builtin_amdgcn_mfma_f32_16x16x32_bf16(
                        wfr[nt][kcl], ax[rt], acc[rt][nt], 0, 0, 0);
        }
    }

    // epilogue: dequant + fp32 float4 stores (4 consecutive n per lane)
    #pragma unroll
    for (int rt = 0; rt < 2; ++rt) {
        int m = rowb + mg * 32 + rt * 16 + laneR;
        float xs = xscale[m];
        #pragma unroll
        for (int nt = 0; nt < 4; ++nt) {
            int nb = col * BN + ng * 64 + (nt << 4) + ((lane >> 4) << 2);
            float4 wsc = *(const float4*)(wscale + nb);
            floatx4 a = acc[rt][nt];
            float4 o;
            o.x = a[0] * xs * wsc.x;
            o.y = a[1] * xs * wsc.y;
            o.z = a[2] * xs * wsc.z;
            o.w = a[3] * xs * wsc.w;
            *(float4*)(out + (size_t)m * N_DIM + nb) = o;
        }
    }
}

extern "C" void kernel_launch(void* const* d_in, const int* in_sizes, int n_in,
                              void* d_out, int out_size, void* d_ws, size_t ws_size,
                              hipStream_t stream) {
    const float* x      = (const float*)d_in[0];
    const float* xscale = (const float*)d_in[1];
    const float* w      = (const float*)d_in[2];
    const float* wscale = (const float*)d_in[3];
    float* out          = (float*)d_out;

    const int M = in_sizes[0] / K_DIM;            // 131072
    const int grid = (M / BM) * 4;                // 8192 (row-tile x col-quarter)
    const int chunkPerXcd = grid / 8;             // 1024 (grid % 8 == 0: bijective)

    if (ws_size >= (size_t)(N_DIM * K_DIM * sizeof(unsigned short))) {
        __bf16* wfp = (__bf16*)d_ws;
        wconv_kernel<<<dim3(64), dim3(512), 0, stream>>>(w, wfp);
        gemm_kernel<true><<<dim3(grid), dim3(256), 0, stream>>>(
            x, xscale, wfp, w, wscale, out, chunkPerXcd);
    } else {
        gemm_kernel<false><<<dim3(grid), dim3(256), 0, stream>>>(
            x, xscale, nullptr, w, wscale, out, chunkPerXcd);
    }
}